// Round 12
// baseline (183.151 us; speedup 1.0000x reference)
//
#include <hip/hip_runtime.h>
#include <hip/hip_bf16.h>
#include <stdint.h>

#define NN 8192
#define FIN 512
#define HID 256

typedef short bf16x8 __attribute__((ext_vector_type(8)));
typedef float f32x4 __attribute__((ext_vector_type(4)));

__device__ __forceinline__ uint32_t pk2(float lo, float hi) {
  uint32_t a = __float_as_uint(lo), b = __float_as_uint(hi);
  a = (a + 0x7FFFu + ((a >> 16) & 1u)) >> 16;
  b = (b + 0x7FFFu + ((b >> 16) & 1u)) >> 16;
  return a | (b << 16);
}

// workspace byte offsets
#define OFF_SEQB   0u         // 8192*512*2  = 8388608
#define OFF_WTB    8388608u   // 256*512*2   = 262144
#define OFF_FTST   8650752u   // 256*8192*2  = 4194304 (packed swizzled 32-j tiles)
#define OFF_F1     12845056u  // 8192*4
#define OFF_F2     12877824u  // 8192*4
#define OFF_Z      12910592u  // 8192*4
#define OFF_F2MAX  12943360u  // 4

// ---- seq f32 -> bf16 ----
__global__ void k_cvt_seq(const float* __restrict__ seq, short* __restrict__ seqb) {
  int i = (blockIdx.x * 256 + threadIdx.x) * 4;
  float4 v = *(const float4*)(seq + i);
  uint2 o; o.x = pk2(v.x, v.y); o.y = pk2(v.z, v.w);
  *(uint2*)(seqb + i) = o;
}

// ---- W[512,256] -> WT bf16 [256,512] ----
__global__ void k_wt(const float* __restrict__ W, short* __restrict__ WTb) {
  int h = blockIdx.x;
  int t = threadIdx.x;
  int k = t * 2;
  float w0 = W[k * 256 + h], w1 = W[(k + 1) * 256 + h];
  ((uint32_t*)(WTb + h * 512))[t] = pk2(w0, w1);
}

// ---- projection GEMM: fts = seq@W; epilogue writes PACKED SWIZZLED ftsP (32-j tiles) ----
// ftsP layout v2: per 32-node tile (16KB = 8192 shorts): [h 0..255][slot 0..3][8 bf16]
//   slot s of row h holds nodes j = tile*32 + (s ^ ((h>>1)&3))*8 .. +7   (XOR bank swizzle;
//   64-lane ds_read_b128 spreads 8 lanes per 4-bank granule = b128 minimum phases)
__global__ __launch_bounds__(256) void k_proj(
    const short* __restrict__ seqb, const short* __restrict__ WTb,
    const float* __restrict__ a1, const float* __restrict__ b1,
    const float* __restrict__ a2, const float* __restrict__ b2,
    short* __restrict__ ftsP, float* __restrict__ f1g, float* __restrict__ f2g,
    uint32_t* __restrict__ f2maxenc) {
  __shared__ short At[64][72];
  __shared__ float f1a[64], f2a[64];
  const int t = threadIdx.x;
  const int l = t & 63, w = t >> 6;
  const int lr = l & 15, lg = l >> 4;
  const int R0 = blockIdx.x * 64;
  const int srow = t >> 2, scol = (t & 3) * 16;
  f32x4 acc[4][4] = {};
  if (t < 64) { f1a[t] = 0.f; f2a[t] = 0.f; }
  for (int kt = 0; kt < FIN; kt += 64) {
    uint4 s0 = *(const uint4*)(seqb + (size_t)(R0 + srow) * FIN + kt + scol);
    uint4 s1 = *(const uint4*)(seqb + (size_t)(R0 + srow) * FIN + kt + scol + 8);
    __syncthreads();
    *(uint4*)&At[srow][scol] = s0;
    *(uint4*)&At[srow][scol + 8] = s1;
    __syncthreads();
#pragma unroll
    for (int kk = 0; kk < 2; ++kk) {
      bf16x8 af[4];
#pragma unroll
      for (int mf = 0; mf < 4; ++mf)
        af[mf] = *(const bf16x8*)&At[mf * 16 + lr][kk * 32 + lg * 8];
#pragma unroll
      for (int nf = 0; nf < 4; ++nf) {
        int h = w * 64 + nf * 16 + lr;
        bf16x8 bfr = *(const bf16x8*)(WTb + h * FIN + kt + kk * 32 + lg * 8);
#pragma unroll
        for (int mf = 0; mf < 4; ++mf)
          acc[mf][nf] = __builtin_amdgcn_mfma_f32_16x16x32_bf16(af[mf], bfr, acc[mf][nf], 0, 0, 0);
      }
    }
  }
  __syncthreads();
  float a1v[4], a2v[4];
#pragma unroll
  for (int nf = 0; nf < 4; ++nf) {
    int h = w * 64 + nf * 16 + lr;
    a1v[nf] = a1[h]; a2v[nf] = a2[h];
  }
#pragma unroll
  for (int mf = 0; mf < 4; ++mf) {
    const int jo = mf * 16 + lg * 4;                 // node offset in this 64-row block
    const int tile2 = (blockIdx.x << 1) | (jo >> 5); // 32-node tile index
    const int jt32 = jo & 31;
    const int slot = (jt32 >> 3) ^ ((lr >> 1) & 3);  // (h>>1)&3 == (lr>>1)&3 (h = 16k + lr)
#pragma unroll
    for (int nf = 0; nf < 4; ++nf) {
      int h = w * 64 + nf * 16 + lr;
      uint2 o; o.x = pk2(acc[mf][nf][0], acc[mf][nf][1]);
      o.y = pk2(acc[mf][nf][2], acc[mf][nf][3]);
      *(uint2*)(ftsP + (size_t)tile2 * 8192 + h * 32 + slot * 8 + (jo & 7)) = o;
    }
#pragma unroll
    for (int e = 0; e < 4; ++e) {
      float p1 = 0.f, p2 = 0.f;
#pragma unroll
      for (int nf = 0; nf < 4; ++nf) { p1 += acc[mf][nf][e] * a1v[nf]; p2 += acc[mf][nf][e] * a2v[nf]; }
#pragma unroll
      for (int m = 8; m >= 1; m >>= 1) { p1 += __shfl_xor(p1, m, 16); p2 += __shfl_xor(p2, m, 16); }
      if (lr == 0) {
        atomicAdd(&f1a[mf * 16 + lg * 4 + e], p1);
        atomicAdd(&f2a[mf * 16 + lg * 4 + e], p2);
      }
    }
  }
  __syncthreads();
  if (t < 64) {
    float v1 = f1a[t] + b1[0];
    float v2 = f2a[t] + b2[0];
    f1g[R0 + t] = v1; f2g[R0 + t] = v2;
    uint32_t u = __float_as_uint(v2);
    u = (u & 0x80000000u) ? ~u : (u | 0x80000000u);
    atomicMax(f2maxenc, u);
  }
}

// ---- fused flash v3: BARRIER-FREE wave-private pipeline ----
// 256 thr = 4 waves (rg = rows-32 group, hh = h-half); each wave owns a PRIVATE 2x8KB LDS
// double-buffer holding its hh-half of the current/next 32-j V tile. No __syncthreads /
// s_barrier in the whole kernel: each wave free-runs with counted per-wave vmcnt.
// Depth-2 prefetch of V (global_load_lds) and bias/f2 (48 VGPR, named stages A/B).
// vmcnt ledger (steady state, at iter top): outstanding = L(tt)6 + S(tt)8 + L(tt+1)6 +
// S(tt+1)8 = 28 -> vmcnt(14) retires exactly {L(tt), S(tt)}. Last iter peeled w/ vmcnt(0).
// pk2 pack (NOT cvt_pk asm -- R6 corruption). Grid (128 i, 4 j) = 2 blocks/CU.
__global__ __launch_bounds__(256, 2) void k_flash(
    const float* __restrict__ bias, const short* __restrict__ ftsP,
    const float* __restrict__ f1g, const float* __restrict__ f2g,
    const uint32_t* __restrict__ f2maxenc,
    float* __restrict__ outacc, float* __restrict__ Zg) {
  __shared__ short Vb[4][2][4096];        // per-wave private double buffers (4 x 2 x 8KB)
  const int t = threadIdx.x;
  const int l = t & 63, wid = t >> 6;     // 4 waves
  const int lr = l & 15, lg = l >> 4;
  const int hh = wid & 1;                 // h-half: h in [hh*128, hh*128+128)
  const int rg = wid >> 1;                // row group
  const int rbase = blockIdx.x * 64 + rg * 32;
  const int rowA = rbase + lr;            // rset0; rset1 = rowA+16
  const int jbase = blockIdx.y * 2048;
  const int jt0 = jbase >> 5;             // 32-j tile index base
  const int NT = 64;                      // 2048/32 tiles per chunk

  uint32_t ue = *f2maxenc;
  float f2mx = __uint_as_float((ue & 0x80000000u) ? (ue ^ 0x80000000u) : ~ue);
  float f1v0 = f1g[rowA];
  float f1v1 = f1g[rowA + 16];
  float x0 = f1v0 + f2mx, x1 = f1v1 + f2mx;
  float mr0 = fmaxf(x0, 0.2f * x0);       // exact row max (bias<=0, lrelu monotone)
  float mr1 = fmaxf(x1, 0.2f * x1);

  const float* bp0 = bias + (size_t)rowA * NN + jbase + lg * 8;
  const float* bp1 = bp0 + (size_t)16 * NN;
  const float* qp = f2g + jbase + lg * 8;

  const int s0 = lg ^ ((lr >> 1) & 3);    // swizzled slot for this lane's j-group
  const short* vrbase0 = &Vb[wid][0][lr * 32 + s0 * 8];
  const short* vrbase1 = &Vb[wid][1][lr * 32 + s0 * 8];

  f32x4 acc0[8] = {};                     // rset0: 16 rows x 128 h
  f32x4 acc1[8] = {};                     // rset1
  float z0 = 0.f, z1 = 0.f;
  float4 bbA[2][2], qqA[2];               // bias/f2 stage A (even tiles): 6 float4
  float4 bbB[2][2], qqB[2];               // stage B (odd tiles)

  // wave stages its 8KB hh-half of a 16KB 32-j tile into ITS OWN buffer (8 x gll dwordx4)
#define STAGE(TT, BUF)                                                          \
  if ((TT) < NT) {                                                              \
    const short* gs = ftsP + (size_t)(jt0 + (TT)) * 8192 + hh * 4096 + l * 8;   \
    _Pragma("unroll")                                                           \
    for (int c = 0; c < 8; ++c)                                                 \
      __builtin_amdgcn_global_load_lds(                                         \
          (const __attribute__((address_space(1))) void*)(gs + c * 512),        \
          (__attribute__((address_space(3))) void*)&Vb[wid][(BUF)][c * 512],    \
          16, 0, 0);                                                            \
  }
  // 6 vmem loads: 4 bias (2 rset x 2 float4) + 2 f2
#define LOADB(TT, BB, QQ)                                                       \
  if ((TT) < NT) {                                                              \
    BB[0][0] = *(const float4*)(bp0 + (TT) * 32);                               \
    BB[0][1] = *(const float4*)(bp0 + (TT) * 32 + 4);                           \
    BB[1][0] = *(const float4*)(bp1 + (TT) * 32);                               \
    BB[1][1] = *(const float4*)(bp1 + (TT) * 32 + 4);                           \
    QQ[0]    = *(const float4*)(qp  + (TT) * 32);                               \
    QQ[1]    = *(const float4*)(qp  + (TT) * 32 + 4);                           \
  }
  // 8 probabilities -> one A-frag (pk2 RNE pack)
#define EHALF(F1V, MR, B0, B1, Q0, Q1, ZACC, AOUT)                              \
  {                                                                             \
    float p[8];                                                                 \
    _Pragma("unroll")                                                           \
    for (int e = 0; e < 4; ++e) {                                               \
      float s = (F1V) + ((const float*)&(Q0))[e];                               \
      float ls = fmaxf(s, 0.2f * s);                                            \
      p[e] = __expf(ls + ((const float*)&(B0))[e] - (MR));                      \
    }                                                                           \
    _Pragma("unroll")                                                           \
    for (int e = 0; e < 4; ++e) {                                               \
      float s = (F1V) + ((const float*)&(Q1))[e];                               \
      float ls = fmaxf(s, 0.2f * s);                                            \
      p[4 + e] = __expf(ls + ((const float*)&(B1))[e] - (MR));                  \
    }                                                                           \
    ZACC += ((p[0] + p[1]) + (p[2] + p[3])) + ((p[4] + p[5]) + (p[6] + p[7]));  \
    union { bf16x8 v; uint32_t u[4]; } A;                                       \
    A.u[0] = pk2(p[0], p[1]); A.u[1] = pk2(p[2], p[3]);                         \
    A.u[2] = pk2(p[4], p[5]); A.u[3] = pk2(p[6], p[7]);                         \
    AOUT = A.v;                                                                 \
  }
  // one tile iter (wave-private): wait -> E -> LOADB(tt+2) -> MFMA -> STAGE(tt+2)
#define ITER(TT, CUR, BB, QQ, VMSTR)                                            \
  {                                                                             \
    asm volatile(VMSTR);                                                        \
    __builtin_amdgcn_sched_barrier(0);                                          \
    bf16x8 A0, A1;                                                              \
    EHALF(f1v0, mr0, BB[0][0], BB[0][1], QQ[0], QQ[1], z0, A0)                  \
    EHALF(f1v1, mr1, BB[1][0], BB[1][1], QQ[0], QQ[1], z1, A1)                  \
    LOADB((TT) + 2, BB, QQ)                                                     \
    __builtin_amdgcn_s_setprio(1);                                              \
    {                                                                           \
      const short* vr = (CUR) ? vrbase1 : vrbase0;                              \
      _Pragma("unroll")                                                         \
      for (int nf = 0; nf < 8; ++nf) {                                          \
        bf16x8 B = *(const bf16x8*)(vr + nf * 512);                             \
        acc0[nf] = __builtin_amdgcn_mfma_f32_16x16x32_bf16(A0, B, acc0[nf], 0, 0, 0); \
        acc1[nf] = __builtin_amdgcn_mfma_f32_16x16x32_bf16(A1, B, acc1[nf], 0, 0, 0); \
      }                                                                         \
    }                                                                           \
    __builtin_amdgcn_s_setprio(0);                                              \
    __builtin_amdgcn_sched_barrier(0);                                          \
    STAGE((TT) + 2, (CUR))                                                      \
  }

  // prologue: order matters for the vmcnt ledger: S0, L0, S1, L1  (no barrier!)
  STAGE(0, 0)
  LOADB(0, bbA, qqA)
  STAGE(1, 1)
  LOADB(1, bbB, qqB)

  for (int tt = 0; tt < NT - 2; tt += 2) {
    ITER(tt, 0, bbA, qqA, "s_waitcnt vmcnt(14)")
    ITER(tt + 1, 1, bbB, qqB, "s_waitcnt vmcnt(14)")
  }
  ITER(NT - 2, 0, bbA, qqA, "s_waitcnt vmcnt(14)")
  ITER(NT - 1, 1, bbB, qqB, "s_waitcnt vmcnt(0)")   // peeled: only 14 outstanding here
#undef ITER
#undef EHALF
#undef LOADB
#undef STAGE

  // Z partials: hh=0 only (hh=1 computed identical E)
  z0 += __shfl_xor(z0, 16); z0 += __shfl_xor(z0, 32);
  z1 += __shfl_xor(z1, 16); z1 += __shfl_xor(z1, 32);
  if (hh == 0 && lg == 0) {
    atomicAdd(&Zg[rowA], z0);
    atomicAdd(&Zg[rowA + 16], z1);
  }

  // numerator partials (C layout: row = lg*4+e, col = hh*128 + nf*16 + lr)
#pragma unroll
  for (int nf = 0; nf < 8; ++nf) {
    int col = hh * 128 + nf * 16 + lr;
#pragma unroll
    for (int e = 0; e < 4; ++e) {
      atomicAdd(&outacc[(size_t)(rbase + lg * 4 + e) * HID + col], acc0[nf][e]);
      atomicAdd(&outacc[(size_t)(rbase + 16 + lg * 4 + e) * HID + col], acc1[nf][e]);
    }
  }
}

// ---- finalize: out = elu(num/Z + bias_zero) ----
__global__ void k_final(float* __restrict__ outp, const float* __restrict__ Zg,
                        const float* __restrict__ bz) {
  int i4 = (blockIdx.x * 256 + threadIdx.x) * 4;
  int row = i4 >> 8;
  int col = i4 & 255;
  float4 v = *(float4*)(outp + i4);
  float zr = 1.0f / Zg[row];
  float4 b = *(const float4*)(bz + col);
  float r[4] = {v.x * zr + b.x, v.y * zr + b.y, v.z * zr + b.z, v.w * zr + b.w};
#pragma unroll
  for (int e = 0; e < 4; ++e) r[e] = r[e] > 0.f ? r[e] : (__expf(r[e]) - 1.f);
  *(float4*)(outp + i4) = make_float4(r[0], r[1], r[2], r[3]);
}

extern "C" void kernel_launch(void* const* d_in, const int* in_sizes, int n_in,
                              void* d_out, int out_size, void* d_ws, size_t ws_size,
                              hipStream_t stream) {
  const float* seq  = (const float*)d_in[0];
  const float* bias = (const float*)d_in[1];
  const float* W    = (const float*)d_in[2];
  const float* a1   = (const float*)d_in[3];
  const float* b1   = (const float*)d_in[4];
  const float* a2   = (const float*)d_in[5];
  const float* b2   = (const float*)d_in[6];
  const float* bz   = (const float*)d_in[7];
  float* out = (float*)d_out;
  char* ws = (char*)d_ws;
  short* seqb = (short*)(ws + OFF_SEQB);
  short* WTb  = (short*)(ws + OFF_WTB);
  short* ftsP = (short*)(ws + OFF_FTST);
  float* f1g  = (float*)(ws + OFF_F1);
  float* f2g  = (float*)(ws + OFF_F2);
  float* Zg   = (float*)(ws + OFF_Z);
  uint32_t* f2m = (uint32_t*)(ws + OFF_F2MAX);

  hipMemsetAsync(d_out, 0, (size_t)NN * HID * 4, stream);
  hipMemsetAsync(Zg, 0, NN * 4, stream);
  hipMemsetAsync(f2m, 0, 4, stream);

  k_cvt_seq<<<4096, 256, 0, stream>>>(seq, seqb);
  k_wt<<<256, 256, 0, stream>>>(W, WTb);
  k_proj<<<128, 256, 0, stream>>>(seqb, WTb, a1, b1, a2, b2, ftsP, f1g, f2g, f2m);
  k_flash<<<dim3(128, 4), 256, 0, stream>>>(bias, ftsP, f1g, f2g, f2m, out, Zg);
  k_final<<<2048, 256, 0, stream>>>(out, Zg, bz);
}

// Round 14
// 173.959 us; speedup vs baseline: 1.0528x; 1.0528x over previous
//
#include <hip/hip_runtime.h>
#include <hip/hip_bf16.h>
#include <stdint.h>

#define NN 8192
#define FIN 512
#define HID 256

typedef short bf16x8 __attribute__((ext_vector_type(8)));
typedef float f32x4 __attribute__((ext_vector_type(4)));

__device__ __forceinline__ uint32_t pk2(float lo, float hi) {
  uint32_t a = __float_as_uint(lo), b = __float_as_uint(hi);
  a = (a + 0x7FFFu + ((a >> 16) & 1u)) >> 16;
  b = (b + 0x7FFFu + ((b >> 16) & 1u)) >> 16;
  return a | (b << 16);
}

// workspace byte offsets
#define OFF_SEQB   0u         // 8192*512*2  = 8388608
#define OFF_WTB    8388608u   // 256*512*2   = 262144
#define OFF_FTST   8650752u   // 256*8192*2  = 4194304 (packed swizzled 64-j tiles)
#define OFF_F1     12845056u  // 8192*4
#define OFF_F2     12877824u  // 8192*4
#define OFF_Z      12910592u  // 8192*4
#define OFF_F2MAX  12943360u  // 4

// ---- seq f32 -> bf16 ----
__global__ void k_cvt_seq(const float* __restrict__ seq, short* __restrict__ seqb) {
  int i = (blockIdx.x * 256 + threadIdx.x) * 4;
  float4 v = *(const float4*)(seq + i);
  uint2 o; o.x = pk2(v.x, v.y); o.y = pk2(v.z, v.w);
  *(uint2*)(seqb + i) = o;
}

// ---- W[512,256] -> WT bf16 [256,512] ----
__global__ void k_wt(const float* __restrict__ W, short* __restrict__ WTb) {
  int h = blockIdx.x;
  int t = threadIdx.x;
  int k = t * 2;
  float w0 = W[k * 256 + h], w1 = W[(k + 1) * 256 + h];
  ((uint32_t*)(WTb + h * 512))[t] = pk2(w0, w1);
}

// ---- projection GEMM: fts = seq@W; epilogue writes PACKED SWIZZLED ftsP, f1, f2, f2max ----
// ftsP layout (R4/R5-proven): per 64-node tile (32KB = 16384 shorts): [h 0..255][slot 0..7][8]
//   slot s of row h holds nodes j = tile*64 + (s^(h&7))*8 .. +7  (XOR bank swizzle)
__global__ __launch_bounds__(256) void k_proj(
    const short* __restrict__ seqb, const short* __restrict__ WTb,
    const float* __restrict__ a1, const float* __restrict__ b1,
    const float* __restrict__ a2, const float* __restrict__ b2,
    short* __restrict__ ftsP, float* __restrict__ f1g, float* __restrict__ f2g,
    uint32_t* __restrict__ f2maxenc) {
  __shared__ short At[64][72];
  __shared__ float f1a[64], f2a[64];
  const int t = threadIdx.x;
  const int l = t & 63, w = t >> 6;
  const int lr = l & 15, lg = l >> 4;
  const int R0 = blockIdx.x * 64;
  const int srow = t >> 2, scol = (t & 3) * 16;
  f32x4 acc[4][4] = {};
  if (t < 64) { f1a[t] = 0.f; f2a[t] = 0.f; }
  for (int kt = 0; kt < FIN; kt += 64) {
    uint4 s0 = *(const uint4*)(seqb + (size_t)(R0 + srow) * FIN + kt + scol);
    uint4 s1 = *(const uint4*)(seqb + (size_t)(R0 + srow) * FIN + kt + scol + 8);
    __syncthreads();
    *(uint4*)&At[srow][scol] = s0;
    *(uint4*)&At[srow][scol + 8] = s1;
    __syncthreads();
#pragma unroll
    for (int kk = 0; kk < 2; ++kk) {
      bf16x8 af[4];
#pragma unroll
      for (int mf = 0; mf < 4; ++mf)
        af[mf] = *(const bf16x8*)&At[mf * 16 + lr][kk * 32 + lg * 8];
#pragma unroll
      for (int nf = 0; nf < 4; ++nf) {
        int h = w * 64 + nf * 16 + lr;
        bf16x8 bfr = *(const bf16x8*)(WTb + h * FIN + kt + kk * 32 + lg * 8);
#pragma unroll
        for (int mf = 0; mf < 4; ++mf)
          acc[mf][nf] = __builtin_amdgcn_mfma_f32_16x16x32_bf16(af[mf], bfr, acc[mf][nf], 0, 0, 0);
      }
    }
  }
  __syncthreads();
  float a1v[4], a2v[4];
#pragma unroll
  for (int nf = 0; nf < 4; ++nf) {
    int h = w * 64 + nf * 16 + lr;
    a1v[nf] = a1[h]; a2v[nf] = a2[h];
  }
#pragma unroll
  for (int mf = 0; mf < 4; ++mf) {
    const int jo = mf * 16 + lg * 4;
    const int slot = (jo >> 3) ^ (lr & 7);
#pragma unroll
    for (int nf = 0; nf < 4; ++nf) {
      int h = w * 64 + nf * 16 + lr;
      uint2 o; o.x = pk2(acc[mf][nf][0], acc[mf][nf][1]);
      o.y = pk2(acc[mf][nf][2], acc[mf][nf][3]);
      *(uint2*)(ftsP + (size_t)blockIdx.x * 16384 + h * 64 + slot * 8 + (jo & 7)) = o;
    }
#pragma unroll
    for (int e = 0; e < 4; ++e) {
      float p1 = 0.f, p2 = 0.f;
#pragma unroll
      for (int nf = 0; nf < 4; ++nf) { p1 += acc[mf][nf][e] * a1v[nf]; p2 += acc[mf][nf][e] * a2v[nf]; }
#pragma unroll
      for (int m = 8; m >= 1; m >>= 1) { p1 += __shfl_xor(p1, m, 16); p2 += __shfl_xor(p2, m, 16); }
      if (lr == 0) {
        atomicAdd(&f1a[mf * 16 + lg * 4 + e], p1);
        atomicAdd(&f2a[mf * 16 + lg * 4 + e], p2);
      }
    }
  }
  __syncthreads();
  if (t < 64) {
    float v1 = f1a[t] + b1[0];
    float v2 = f2a[t] + b2[0];
    f1g[R0 + t] = v1; f2g[R0 + t] = v2;
    uint32_t u = __float_as_uint(v2);
    u = (u & 0x80000000u) ? ~u : (u | 0x80000000u);
    atomicMax(f2maxenc, u);
  }
}

// ---- fused flash (R5 skeleton, 157us proven) + PAGE-LOCAL bias batching ----
// 256 thr = 4 waves x 16 rows, all 256 h per wave; grid (128 i, 4 j); V via global_load_lds
// 2x32KB dbuf, 1 __syncthreads/tile (all R5-proven, numerics bit-identical).
// ONE CHANGE vs R5: bias loaded 4 tiles per batch (1KB CONTIGUOUS per row instead of 256B)
// into 4 named stages S0..S3, refilled at each quad's last iter. Attacks the measured
// DRAM-page-efficiency limit (bias stream ran at 1.8 TB/s: 256B/row per page-open).
// f2 keeps R5's depth-2 qq/nq. pk2 pack (NOT cvt_pk asm -- R6 corruption).
__global__ __launch_bounds__(256, 2) void k_flash(
    const float* __restrict__ bias, const short* __restrict__ ftsP,
    const float* __restrict__ f1g, const float* __restrict__ f2g,
    const uint32_t* __restrict__ f2maxenc,
    float* __restrict__ outacc, float* __restrict__ Zg) {
  __shared__ short Vb[2][16384];  // 2 x 32KB double buffer
  const int t = threadIdx.x;
  const int l = t & 63, wid = t >> 6;
  const int lr = l & 15, lg = l >> 4;
  const int rbase = blockIdx.x * 64 + wid * 16;
  const int rowA = rbase + lr;
  const int jbase = blockIdx.y * 2048;
  const int jt0 = jbase >> 6;
  const int NT = 32;

  uint32_t ue = *f2maxenc;
  float f2mx = __uint_as_float((ue & 0x80000000u) ? (ue ^ 0x80000000u) : ~ue);
  float f1v = f1g[rowA];
  float xm = f1v + f2mx;
  float mr = fmaxf(xm, 0.2f * xm);  // exact row max (bias<=0, lrelu monotone)

  const float* bp = bias + (size_t)rowA * NN + jbase + lg * 8;
  const float* qp = f2g + jbase + lg * 8;

  const int s0 = lg ^ (lr & 7);   // kk=0 slot (conflict-free; 0 conflicts R4-R12)
  const int s1 = s0 ^ 4;          // kk=1 slot

  f32x4 acc[16] = {};
  float z = 0.f;
  float4 bbS0[2][2], bbS1[2][2], bbS2[2][2], bbS3[2][2];  // 4 bias stages (64 VGPR)
  float4 qq[2][2], nq[2][2];                              // f2 depth-2 (R5 scheme)

#define STAGE(TT, BUF)                                                          \
  if ((TT) < NT) {                                                              \
    const short* gs = ftsP + (size_t)(jt0 + (TT)) * 16384 + wid * 4096 + l * 8; \
    _Pragma("unroll")                                                           \
    for (int c = 0; c < 8; ++c)                                                 \
      __builtin_amdgcn_global_load_lds(                                         \
          (const __attribute__((address_space(1))) void*)(gs + c * 512),        \
          (__attribute__((address_space(3))) void*)&Vb[(BUF)][wid * 4096 + c * 512], \
          16, 0, 0);                                                            \
  }
  // one tile's bias into one stage (4 x float4; addresses as R5)
#define LB1(TT, B)                                                              \
  if ((TT) < NT) {                                                              \
    B[0][0] = *(const float4*)(bp + (TT) * 64);                                 \
    B[0][1] = *(const float4*)(bp + (TT) * 64 + 4);                             \
    B[1][0] = *(const float4*)(bp + (TT) * 64 + 32);                            \
    B[1][1] = *(const float4*)(bp + (TT) * 64 + 36);                            \
  }
  // 4 consecutive tiles = 1KB contiguous per row -> DRAM page locality
#define LOADB4(T0) LB1((T0), bbS0) LB1((T0) + 1, bbS1) LB1((T0) + 2, bbS2) LB1((T0) + 3, bbS3)
#define LOADF(TT, Q)                                                            \
  if ((TT) < NT) {                                                              \
    Q[0][0] = *(const float4*)(qp + (TT) * 64);                                 \
    Q[0][1] = *(const float4*)(qp + (TT) * 64 + 4);                             \
    Q[1][0] = *(const float4*)(qp + (TT) * 64 + 32);                            \
    Q[1][1] = *(const float4*)(qp + (TT) * 64 + 36);                            \
  }
  // 8 probabilities -> one A-frag (pk2 RNE pack, bit-proven)
#define EHALF(BBK, QQK, AOUT)                                                   \
  {                                                                             \
    float p[8];                                                                 \
    _Pragma("unroll")                                                           \
    for (int e = 0; e < 4; ++e) {                                               \
      float s = f1v + ((const float*)&QQK[0])[e];                               \
      float ls = fmaxf(s, 0.2f * s);                                            \
      p[e] = __expf(ls + ((const float*)&BBK[0])[e] - mr);                      \
    }                                                                           \
    _Pragma("unroll")                                                           \
    for (int e = 0; e < 4; ++e) {                                               \
      float s = f1v + ((const float*)&QQK[1])[e];                               \
      float ls = fmaxf(s, 0.2f * s);                                            \
      p[4 + e] = __expf(ls + ((const float*)&BBK[1])[e] - mr);                  \
    }                                                                           \
    z += ((p[0] + p[1]) + (p[2] + p[3])) + ((p[4] + p[5]) + (p[6] + p[7]));     \
    union { bf16x8 v; uint32_t u[4]; } A;                                       \
    A.u[0] = pk2(p[0], p[1]); A.u[1] = pk2(p[2], p[3]);                         \
    A.u[2] = pk2(p[4], p[5]); A.u[3] = pk2(p[6], p[7]);                         \
    AOUT = A.v;                                                                 \
  }
  // one tile iter (R5 structure): E -> [batch refill if quad-last] -> MFMA -> sync -> STAGE
#define ITER(TT, SS, DO4)                                                       \
  {                                                                             \
    bf16x8 A0, A1;                                                              \
    EHALF(SS[0], qq[0], A0)                                                     \
    EHALF(SS[1], qq[1], A1)                                                     \
    LOADF((TT) + 1, nq)                                                         \
    if (DO4) { LOADB4((TT) + 1) }                                               \
    {                                                                           \
      const int cb = (TT) & 1;                                                  \
      const short* vr0 = &Vb[cb][lr * 64 + s0 * 8];                             \
      const short* vr1 = &Vb[cb][lr * 64 + s1 * 8];                             \
      _Pragma("unroll")                                                         \
      for (int nf = 0; nf < 16; ++nf) {                                         \
        bf16x8 B0 = *(const bf16x8*)(vr0 + nf * 1024);                          \
        acc[nf] = __builtin_amdgcn_mfma_f32_16x16x32_bf16(A0, B0, acc[nf], 0, 0, 0); \
      }                                                                         \
      _Pragma("unroll")                                                         \
      for (int nf = 0; nf < 16; ++nf) {                                         \
        bf16x8 B1 = *(const bf16x8*)(vr1 + nf * 1024);                          \
        acc[nf] = __builtin_amdgcn_mfma_f32_16x16x32_bf16(A1, B1, acc[nf], 0, 0, 0); \
      }                                                                         \
    }                                                                           \
    __syncthreads();                                                            \
    STAGE((TT) + 2, (TT) & 1)                                                   \
    _Pragma("unroll")                                                           \
    for (int kk = 0; kk < 2; ++kk) {                                            \
      qq[kk][0] = nq[kk][0]; qq[kk][1] = nq[kk][1];                             \
    }                                                                           \
  }

  // prologue: V tiles 0,1 -> LDS; bias tiles 0..3 -> S0..S3; f2 tile 0 -> qq
  STAGE(0, 0)
  STAGE(1, 1)
  LOADB4(0)
  LOADF(0, qq)
  __syncthreads();

  for (int tt = 0; tt < NT; tt += 4) {
    ITER(tt, bbS0, 0)
    ITER(tt + 1, bbS1, 0)
    ITER(tt + 2, bbS2, 0)
    ITER(tt + 3, bbS3, 1)   // quad-last: all stages consumed -> refill tiles tt+4..tt+7
  }
#undef ITER
#undef EHALF
#undef LOADF
#undef LOADB4
#undef LB1
#undef STAGE

  // Z partials (lanes sharing row lr: lg groups)
  z += __shfl_xor(z, 16);
  z += __shfl_xor(z, 32);
  if (lg == 0) atomicAdd(&Zg[rowA], z);

  // numerator partials (C layout: row = lg*4+e, col = nf*16+lr)
#pragma unroll
  for (int nf = 0; nf < 16; ++nf) {
    int col = nf * 16 + lr;
#pragma unroll
    for (int e = 0; e < 4; ++e)
      atomicAdd(&outacc[(size_t)(rbase + lg * 4 + e) * HID + col], acc[nf][e]);
  }
}

// ---- finalize: out = elu(num/Z + bias_zero) ----
__global__ void k_final(float* __restrict__ outp, const float* __restrict__ Zg,
                        const float* __restrict__ bz) {
  int i4 = (blockIdx.x * 256 + threadIdx.x) * 4;
  int row = i4 >> 8;
  int col = i4 & 255;
  float4 v = *(float4*)(outp + i4);
  float zr = 1.0f / Zg[row];
  float4 b = *(const float4*)(bz + col);
  float r[4] = {v.x * zr + b.x, v.y * zr + b.y, v.z * zr + b.z, v.w * zr + b.w};
#pragma unroll
  for (int e = 0; e < 4; ++e) r[e] = r[e] > 0.f ? r[e] : (__expf(r[e]) - 1.f);
  *(float4*)(outp + i4) = make_float4(r[0], r[1], r[2], r[3]);
}

extern "C" void kernel_launch(void* const* d_in, const int* in_sizes, int n_in,
                              void* d_out, int out_size, void* d_ws, size_t ws_size,
                              hipStream_t stream) {
  const float* seq  = (const float*)d_in[0];
  const float* bias = (const float*)d_in[1];
  const float* W    = (const float*)d_in[2];
  const float* a1   = (const float*)d_in[3];
  const float* b1   = (const float*)d_in[4];
  const float* a2   = (const float*)d_in[5];
  const float* b2   = (const float*)d_in[6];
  const float* bz   = (const float*)d_in[7];
  float* out = (float*)d_out;
  char* ws = (char*)d_ws;
  short* seqb = (short*)(ws + OFF_SEQB);
  short* WTb  = (short*)(ws + OFF_WTB);
  short* ftsP = (short*)(ws + OFF_FTST);
  float* f1g  = (float*)(ws + OFF_F1);
  float* f2g  = (float*)(ws + OFF_F2);
  float* Zg   = (float*)(ws + OFF_Z);
  uint32_t* f2m = (uint32_t*)(ws + OFF_F2MAX);

  hipMemsetAsync(d_out, 0, (size_t)NN * HID * 4, stream);
  hipMemsetAsync(Zg, 0, NN * 4, stream);
  hipMemsetAsync(f2m, 0, 4, stream);

  k_cvt_seq<<<4096, 256, 0, stream>>>(seq, seqb);
  k_wt<<<256, 256, 0, stream>>>(W, WTb);
  k_proj<<<128, 256, 0, stream>>>(seqb, WTb, a1, b1, a2, b2, ftsP, f1g, f2g, f2m);
  k_flash<<<dim3(128, 4), 256, 0, stream>>>(bias, ftsP, f1g, f2g, f2m, out, Zg);
  k_final<<<2048, 256, 0, stream>>>(out, Zg, bz);
}